// Round 1
// baseline (856.343 us; speedup 1.0000x reference)
//
#include <hip/hip_runtime.h>

// GCN scatter-add: out[v] = sum_{(u,v) in E} features[u]
// features: [100000, 64] f32, src/dst: [1000000] int (harness converts to i32)

#define N_NODES 100000
#define N_EDGES 1000000
#define D_FEAT  64

__global__ void zero_out_kernel(float4* __restrict__ out, int n4) {
    int i = blockIdx.x * blockDim.x + threadIdx.x;
    if (i < n4) out[i] = float4{0.f, 0.f, 0.f, 0.f};
}

// 16 threads per edge; each thread handles one float4 chunk of the 64-wide row.
// Wave of 64 lanes covers 4 edges: lanes 0-15 read edge e's 256B row contiguously
// (coalesced within the row), then 4 atomicAdds per lane to the dst row.
__global__ void scatter_add_kernel(const float* __restrict__ feat,
                                   const int* __restrict__ src,
                                   const int* __restrict__ dst,
                                   float* __restrict__ out,
                                   int n_edges) {
    int t = blockIdx.x * blockDim.x + threadIdx.x;
    int e = t >> 4;          // edge index
    int c = (t & 15) << 2;   // feature offset (0,4,...,60)
    if (e >= n_edges) return;

    int s = src[e];
    int d = dst[e];

    const float4 v = *reinterpret_cast<const float4*>(feat + (size_t)s * D_FEAT + c);
    float* o = out + (size_t)d * D_FEAT + c;

    atomicAdd(o + 0, v.x);
    atomicAdd(o + 1, v.y);
    atomicAdd(o + 2, v.z);
    atomicAdd(o + 3, v.w);
}

extern "C" void kernel_launch(void* const* d_in, const int* in_sizes, int n_in,
                              void* d_out, int out_size, void* d_ws, size_t ws_size,
                              hipStream_t stream) {
    const float* feat = (const float*)d_in[0];
    const int*   src  = (const int*)d_in[1];
    const int*   dst  = (const int*)d_in[2];
    float*       out  = (float*)d_out;

    int n_edges = in_sizes[1];

    // Zero the output (harness poisons it with 0xAA before timing).
    int n4 = out_size / 4;  // out_size = 100000*64 floats, divisible by 4
    int zgrid = (n4 + 255) / 256;
    zero_out_kernel<<<zgrid, 256, 0, stream>>>((float4*)d_out, n4);

    // Scatter-add: 16 threads per edge.
    long long total = (long long)n_edges * 16;
    int grid = (int)((total + 255) / 256);
    scatter_add_kernel<<<grid, 256, 0, stream>>>(feat, src, dst, out, n_edges);
}

// Round 2
// 383.447 us; speedup vs baseline: 2.2333x; 2.2333x over previous
//
#include <hip/hip_runtime.h>

// GCN scatter-add: out[v] = sum_{(u,v) in E} features[u]
// Strategy: build CSR by dst on-device (histogram + scan + reorder),
// then atomic-free gather with one wave (64 lanes) per node.

#define N_NODES 100000
#define N_EDGES 1000000
#define D_FEAT  64
#define SCAN_THREADS 1024

__global__ void zero_ints_kernel(int* __restrict__ p, int n) {
    int i = blockIdx.x * blockDim.x + threadIdx.x;
    if (i < n) p[i] = 0;
}

__global__ void hist_kernel(const int* __restrict__ dst, int* __restrict__ counts, int n) {
    int i = blockIdx.x * blockDim.x + threadIdx.x;
    if (i < n) atomicAdd(&counts[dst[i]], 1);
}

// Single-block chunked exclusive scan over counts[n] -> offsets[], cursor[].
__global__ __launch_bounds__(SCAN_THREADS) void scan_kernel(const int* __restrict__ counts,
                                                            int* __restrict__ offsets,
                                                            int* __restrict__ cursor, int n) {
    __shared__ int lds[SCAN_THREADS];
    int t = threadIdx.x;
    int chunk = (n + SCAN_THREADS - 1) / SCAN_THREADS;
    int lo = t * chunk;
    int hi = min(lo + chunk, n);
    int s = 0;
    for (int i = lo; i < hi; ++i) s += counts[i];
    lds[t] = s;
    __syncthreads();
    // Hillis-Steele inclusive scan over 1024 partials
    for (int off = 1; off < SCAN_THREADS; off <<= 1) {
        int v = (t >= off) ? lds[t - off] : 0;
        __syncthreads();
        lds[t] += v;
        __syncthreads();
    }
    int run = (t == 0) ? 0 : lds[t - 1];
    for (int i = lo; i < hi; ++i) {
        offsets[i] = run;
        cursor[i]  = run;
        run += counts[i];
    }
}

__global__ void reorder_kernel(const int* __restrict__ src, const int* __restrict__ dst,
                               int* __restrict__ cursor, int* __restrict__ csr, int n) {
    int i = blockIdx.x * blockDim.x + threadIdx.x;
    if (i < n) {
        int d = dst[i];
        int pos = atomicAdd(&cursor[d], 1);
        csr[pos] = src[i];
    }
}

// One wave per node; lane = feature column. After reorder, cursor[v] == row end.
__global__ void gather_kernel(const float* __restrict__ feat,
                              const int* __restrict__ offsets,
                              const int* __restrict__ row_end,
                              const int* __restrict__ csr,
                              float* __restrict__ out, int n_nodes) {
    int wid  = (blockIdx.x * blockDim.x + threadIdx.x) >> 6;
    int lane = threadIdx.x & 63;
    if (wid >= n_nodes) return;

    int start = offsets[wid];
    int end   = row_end[wid];

    float acc = 0.f;
    int i = start;
    for (; i + 4 <= end; i += 4) {
        int s0 = csr[i + 0];
        int s1 = csr[i + 1];
        int s2 = csr[i + 2];
        int s3 = csr[i + 3];
        float v0 = feat[(size_t)s0 * D_FEAT + lane];
        float v1 = feat[(size_t)s1 * D_FEAT + lane];
        float v2 = feat[(size_t)s2 * D_FEAT + lane];
        float v3 = feat[(size_t)s3 * D_FEAT + lane];
        acc += v0 + v1 + v2 + v3;
    }
    for (; i < end; ++i) {
        acc += feat[(size_t)csr[i] * D_FEAT + lane];
    }
    out[(size_t)wid * D_FEAT + lane] = acc;
}

extern "C" void kernel_launch(void* const* d_in, const int* in_sizes, int n_in,
                              void* d_out, int out_size, void* d_ws, size_t ws_size,
                              hipStream_t stream) {
    const float* feat = (const float*)d_in[0];
    const int*   src  = (const int*)d_in[1];
    const int*   dst  = (const int*)d_in[2];
    float*       out  = (float*)d_out;

    const int n_edges = in_sizes[1];
    const int n_nodes = N_NODES;

    // Workspace layout: offsets[N] | cursor[N] | csr_src[E]   (4.8 MB total)
    int* offsets = (int*)d_ws;
    int* cursor  = offsets + n_nodes;
    int* csr     = cursor + n_nodes;
    // counts reuses offsets storage initially? No — scan reads counts while
    // writing offsets; keep counts in cursor's slot is also unsafe. Use csr's
    // head? csr is written after scan, so counts can live at csr start only if
    // scan finishes first — it does (stream order). Place counts at csr base.
    int* counts = csr + n_edges - n_nodes;  // last N ints of the csr region? unsafe.
    // Simpler: counts gets its own slot after csr.
    counts = csr + n_edges;

    // 1) zero histogram
    {
        int grid = (n_nodes + 255) / 256;
        zero_ints_kernel<<<grid, 256, 0, stream>>>(counts, n_nodes);
    }
    // 2) histogram of dst
    {
        int grid = (n_edges + 255) / 256;
        hist_kernel<<<grid, 256, 0, stream>>>(dst, counts, n_edges);
    }
    // 3) exclusive scan -> offsets, cursor
    scan_kernel<<<1, SCAN_THREADS, 0, stream>>>(counts, offsets, cursor, n_nodes);
    // 4) reorder src into CSR order by dst (cursor becomes row_end)
    {
        int grid = (n_edges + 255) / 256;
        reorder_kernel<<<grid, 256, 0, stream>>>(src, dst, cursor, csr, n_edges);
    }
    // 5) gather: one wave per node
    {
        long long total = (long long)n_nodes * 64;
        int grid = (int)((total + 255) / 256);
        gather_kernel<<<grid, 256, 0, stream>>>(feat, offsets, cursor, csr, out, n_nodes);
    }
}

// Round 3
// 174.756 us; speedup vs baseline: 4.9002x; 2.1942x over previous
//
#include <hip/hip_runtime.h>

// GCN scatter-add: out[v] = sum_{(u,v) in E} features[u]
// CSR build (hist + device-wide scan + reorder), then atomic-free gather.

#define N_NODES 100000
#define N_EDGES 1000000
#define D_FEAT  64
#define TILE    1024   // scan tile: 256 threads x 4 ints

__global__ void zero_ints_kernel(int* __restrict__ p, int n) {
    int i = blockIdx.x * blockDim.x + threadIdx.x;
    if (i < n) p[i] = 0;
}

__global__ void hist_kernel(const int* __restrict__ dst, int* __restrict__ counts, int n) {
    int i = blockIdx.x * blockDim.x + threadIdx.x;
    if (i < n) atomicAdd(&counts[dst[i]], 1);
}

// Pass 1: per-block tile reduction (coalesced int4 loads).
__global__ void reduce_tiles_kernel(const int* __restrict__ counts,
                                    int* __restrict__ bsums, int n) {
    __shared__ int lds[256];
    int b = blockIdx.x, t = threadIdx.x;
    int base = b * TILE + t * 4;
    int s = 0;
    if (base + 3 < n) {
        int4 v = *reinterpret_cast<const int4*>(counts + base);
        s = v.x + v.y + v.z + v.w;
    } else {
        for (int j = 0; j < 4; ++j) if (base + j < n) s += counts[base + j];
    }
    lds[t] = s;
    __syncthreads();
    for (int off = 128; off > 0; off >>= 1) {
        if (t < off) lds[t] += lds[t + off];
        __syncthreads();
    }
    if (t == 0) bsums[b] = lds[0];
}

// Pass 2: exclusive scan of block sums (nb <= 256) in one small block.
__global__ void scan_bsums_kernel(int* __restrict__ bsums, int nb) {
    __shared__ int lds[256];
    int t = threadIdx.x;
    int v = (t < nb) ? bsums[t] : 0;
    lds[t] = v;
    __syncthreads();
    for (int off = 1; off < 256; off <<= 1) {
        int u = (t >= off) ? lds[t - off] : 0;
        __syncthreads();
        lds[t] += u;
        __syncthreads();
    }
    if (t < nb) bsums[t] = lds[t] - v;  // exclusive
}

// Pass 3: per-block exclusive scan with block offset; write offsets & cursor.
__global__ void scan_tiles_kernel(const int* __restrict__ counts,
                                  const int* __restrict__ bsums,
                                  int* __restrict__ offsets,
                                  int* __restrict__ cursor, int n) {
    __shared__ int lds[256];
    int b = blockIdx.x, t = threadIdx.x;
    int base = b * TILE + t * 4;
    int e0 = 0, e1 = 0, e2 = 0, e3 = 0;
    bool full = (base + 3 < n);
    if (full) {
        int4 v = *reinterpret_cast<const int4*>(counts + base);
        e0 = v.x; e1 = v.y; e2 = v.z; e3 = v.w;
    } else {
        if (base     < n) e0 = counts[base];
        if (base + 1 < n) e1 = counts[base + 1];
        if (base + 2 < n) e2 = counts[base + 2];
    }
    int s = e0 + e1 + e2 + e3;
    lds[t] = s;
    __syncthreads();
    for (int off = 1; off < 256; off <<= 1) {
        int u = (t >= off) ? lds[t - off] : 0;
        __syncthreads();
        lds[t] += u;
        __syncthreads();
    }
    int run = bsums[b] + lds[t] - s;  // exclusive prefix for this thread's 4
    int o0 = run, o1 = o0 + e0, o2 = o1 + e1, o3 = o2 + e2;
    if (full) {
        int4 w = make_int4(o0, o1, o2, o3);
        *reinterpret_cast<int4*>(offsets + base) = w;
        *reinterpret_cast<int4*>(cursor  + base) = w;
    } else {
        if (base     < n) { offsets[base]     = o0; cursor[base]     = o0; }
        if (base + 1 < n) { offsets[base + 1] = o1; cursor[base + 1] = o1; }
        if (base + 2 < n) { offsets[base + 2] = o2; cursor[base + 2] = o2; }
    }
}

__global__ void reorder_kernel(const int* __restrict__ src, const int* __restrict__ dst,
                               int* __restrict__ cursor, int* __restrict__ csr, int n) {
    int i = blockIdx.x * blockDim.x + threadIdx.x;
    if (i < n) {
        int d = dst[i];
        int pos = atomicAdd(&cursor[d], 1);
        csr[pos] = src[i];
    }
}

// One wave per node; lane = feature column. After reorder, cursor[v] == row end.
__global__ void gather_kernel(const float* __restrict__ feat,
                              const int* __restrict__ offsets,
                              const int* __restrict__ row_end,
                              const int* __restrict__ csr,
                              float* __restrict__ out, int n_nodes) {
    int wid  = (blockIdx.x * blockDim.x + threadIdx.x) >> 6;
    int lane = threadIdx.x & 63;
    if (wid >= n_nodes) return;

    int start = offsets[wid];
    int end   = row_end[wid];

    float acc = 0.f;
    int i = start;
    for (; i + 4 <= end; i += 4) {
        int s0 = csr[i + 0];
        int s1 = csr[i + 1];
        int s2 = csr[i + 2];
        int s3 = csr[i + 3];
        float v0 = feat[(size_t)s0 * D_FEAT + lane];
        float v1 = feat[(size_t)s1 * D_FEAT + lane];
        float v2 = feat[(size_t)s2 * D_FEAT + lane];
        float v3 = feat[(size_t)s3 * D_FEAT + lane];
        acc += v0 + v1 + v2 + v3;
    }
    for (; i < end; ++i) {
        acc += feat[(size_t)csr[i] * D_FEAT + lane];
    }
    out[(size_t)wid * D_FEAT + lane] = acc;
}

extern "C" void kernel_launch(void* const* d_in, const int* in_sizes, int n_in,
                              void* d_out, int out_size, void* d_ws, size_t ws_size,
                              hipStream_t stream) {
    const float* feat = (const float*)d_in[0];
    const int*   src  = (const int*)d_in[1];
    const int*   dst  = (const int*)d_in[2];
    float*       out  = (float*)d_out;

    const int n_edges = in_sizes[1];
    const int n_nodes = N_NODES;
    const int nb = (n_nodes + TILE - 1) / TILE;  // 98 tiles

    // Workspace: offsets[N] | cursor[N] | csr[E] | counts[N] | bsums[256]
    int* offsets = (int*)d_ws;
    int* cursor  = offsets + n_nodes;
    int* csr     = cursor + n_nodes;
    int* counts  = csr + n_edges;
    int* bsums   = counts + n_nodes;

    // 1) zero histogram
    zero_ints_kernel<<<(n_nodes + 255) / 256, 256, 0, stream>>>(counts, n_nodes);
    // 2) histogram of dst
    hist_kernel<<<(n_edges + 255) / 256, 256, 0, stream>>>(dst, counts, n_edges);
    // 3) device-wide exclusive scan -> offsets, cursor
    reduce_tiles_kernel<<<nb, 256, 0, stream>>>(counts, bsums, n_nodes);
    scan_bsums_kernel<<<1, 256, 0, stream>>>(bsums, nb);
    scan_tiles_kernel<<<nb, 256, 0, stream>>>(counts, bsums, offsets, cursor, n_nodes);
    // 4) reorder src into CSR order by dst (cursor becomes row_end)
    reorder_kernel<<<(n_edges + 255) / 256, 256, 0, stream>>>(src, dst, cursor, csr, n_edges);
    // 5) gather: one wave per node
    {
        long long total = (long long)n_nodes * 64;
        int grid = (int)((total + 255) / 256);
        gather_kernel<<<grid, 256, 0, stream>>>(feat, offsets, cursor, csr, out, n_nodes);
    }
}